// Round 1
// baseline (63.865 us; speedup 1.0000x reference)
//
#include <hip/hip_runtime.h>

#define G 32
#define NNBR 16
#define ATOM_TYPE 6

// Block: 256 threads = 4 waves. Grid: (B*A, G) = (128, 32) = 4096 blocks.
// Each block handles ONE (b,a) pair and ONE i-plane (32*32 = 1024 voxels =
// 256 float4 -> exactly 1 float4/thread). The i-dependent x-term is fused
// into the ey table at fill time, so the main loop is 2 LDS reads + 4 FMAs
// per masked neighbor.
__global__ __launch_bounds__(256) void voxel_kernel(
    const float* __restrict__ dv,     // (B=4, A=32, N=16, 3)
    const int*   __restrict__ an,     // (A=32, N=16) int32
    const float* __restrict__ sigma,  // (1,)
    float*       __restrict__ out)    // (B, A, G, G, G)
{
    const int ba  = blockIdx.x;        // b*32 + a
    const int a   = ba & 31;
    const int ip  = blockIdx.y;        // i-plane 0..31
    const int tid = threadIdx.x;

    __shared__ __align__(16) float sEyx[NNBR][G];  // exp(coeff*(dx_m^2 + dy_j^2))
    __shared__ __align__(16) float sEz [NNBR][G];  // exp(coeff*dz_k^2)
    __shared__ float sDv[NNBR * 3];
    __shared__ int   sIdx[NNBR];
    __shared__ int   sM;

    // Prefetch distance vectors (48 floats) — issues in parallel with an load.
    if (tid < NNBR * 3) sDv[tid] = dv[(size_t)ba * (NNBR * 3) + tid];

    // Parallel mask compaction: one load per neighbor + ballot prefix-sum.
    // Only wave 0 (tid 0..63) has nonzero flags; sM written by tid 0 (wave 0).
    int flag = 0;
    if (tid < NNBR) flag = (an[a * NNBR + tid] == ATOM_TYPE) ? 1 : 0;
    unsigned long long mask = __ballot(flag);
    if (flag) {
        int pos = __popcll(mask & ((1ull << tid) - 1ull));
        sIdx[pos] = tid;
    }
    if (tid == 0) sM = (int)__popcll(mask);
    __syncthreads();

    const int   M     = sM;
    const float s     = sigma[0];
    const float coeff = -0.5f / (s * s);
    const float step  = 8.0f / 31.0f;         // linspace(-4,4,32) spacing
    const float ti    = -4.0f + (float)ip * step;

    // Fill fused tables for the M masked neighbors (M*32 <= 512 items,
    // 2 exps each, spread over 256 threads -> <= 4 exps/thread).
    for (int idx = tid; idx < M * G; idx += 256) {
        const int m = idx >> 5;
        const int j = idx & 31;
        const int n = sIdx[m];
        const float t  = -4.0f + (float)j * step;
        const float dx = ti - sDv[3 * n + 0];
        const float dy = t  - sDv[3 * n + 1];
        const float dz = t  - sDv[3 * n + 2];
        sEyx[m][j] = __expf(coeff * (dx * dx + dy * dy));
        sEz [m][j] = __expf(coeff * (dz * dz));
    }
    __syncthreads();

    // Thread -> (j, k0): j = tid>>3 (8-lane broadcast on sEyx read, free),
    // k0 = (tid&7)*4 (ds_read_b128, 8 lanes cover one 128B row, conflict-free).
    const int j  = tid >> 3;
    const int k0 = (tid & 7) * 4;

    float4 acc = {0.f, 0.f, 0.f, 0.f};
    for (int m = 0; m < M; ++m) {
        const float  e  = sEyx[m][j];
        const float4 ez = *(const float4*)&sEz[m][k0];
        acc.x += e * ez.x;
        acc.y += e * ez.y;
        acc.z += e * ez.z;
        acc.w += e * ez.w;
    }

    // One coalesced float4 store per thread: block covers a dense 4 KB plane.
    float4* out4 = (float4*)(out + (size_t)ba * (G * G * G) + (size_t)ip * (G * G));
    out4[tid] = acc;
}

extern "C" void kernel_launch(void* const* d_in, const int* in_sizes, int n_in,
                              void* d_out, int out_size, void* d_ws, size_t ws_size,
                              hipStream_t stream) {
    const float* dv    = (const float*)d_in[0];   // (4,32,16,3)
    const int*   an    = (const int*)d_in[1];     // (32,16)
    const float* sigma = (const float*)d_in[2];   // (1,)
    float*       out   = (float*)d_out;           // (4,32,32,32,32)

    dim3 grid(4 * 32, G);
    dim3 block(256);
    voxel_kernel<<<grid, block, 0, stream>>>(dv, an, sigma, out);
}

// Round 2
// 63.798 us; speedup vs baseline: 1.0010x; 1.0010x over previous
//
#include <hip/hip_runtime.h>

#define G 32
#define NNBR 16
#define ATOM_TYPE 6

// Block: 256 threads = 4 waves. Grid: (B*A, G) = (128, 32) = 4096 blocks.
// One (b,a,i-plane) per block, 1 float4/thread output.
// Single-sync design: the neighbor mask is computed redundantly per-wave in
// registers (all waves load the same 16 an values -> identical ballot), so
// no LDS staging / first barrier is needed. ~18% of blocks have M==0 and
// store a zero plane without ever syncing.
__global__ __launch_bounds__(256) void voxel_kernel(
    const float* __restrict__ dv,     // (B=4, A=32, N=16, 3)
    const int*   __restrict__ an,     // (A=32, N=16) int32
    const float* __restrict__ sigma,  // (1,)
    float*       __restrict__ out)    // (B, A, G, G, G)
{
    const int ba   = blockIdx.x;       // b*32 + a
    const int a    = ba & 31;
    const int ip   = blockIdx.y;       // i-plane 0..31
    const int tid  = threadIdx.x;
    const int lane = tid & 63;

    // Per-wave mask: lanes 0..15 of each wave load the same an values (L2-hit),
    // ballot gives the identical 16-bit mask in every wave. No barrier needed.
    int flag = 0;
    if (lane < NNBR) flag = (an[a * NNBR + lane] == ATOM_TYPE) ? 1 : 0;
    const unsigned long long mask = __ballot(flag);
    const int M = (int)__popcll(mask);

    float4* out4 = (float4*)(out + (size_t)ba * (G * G * G) + (size_t)ip * (G * G));

    if (M == 0) {                      // all-zero plane: store and exit early
        out4[tid] = make_float4(0.f, 0.f, 0.f, 0.f);
        return;
    }

    __shared__ __align__(16) float sEyx[NNBR][G];  // exp(coeff*(dx_m^2 + dy_j^2))
    __shared__ __align__(16) float sEz [NNBR][G];  // exp(coeff*dz_k^2)

    const float s     = sigma[0];
    const float coeff = -0.5f / (s * s);
    const float step  = 8.0f / 31.0f;              // linspace(-4,4,32) spacing
    const float ti    = -4.0f + (float)ip * step;

    // Fill fused tables for the M masked neighbors (M*32 <= 512 items,
    // <= 2 items/thread). n = m-th set bit of mask, found by clearing m
    // low set bits (m <= 15, register-only). dv reads are scattered scalar
    // loads but L1/L2-resident (192 B per ba, shared by 32 blocks).
    for (int idx = tid; idx < M * G; idx += 256) {
        const int m = idx >> 5;
        const int j = idx & 31;
        unsigned mm = (unsigned)mask;
        for (int t = 0; t < m; ++t) mm &= mm - 1;
        const int n = __ffs(mm) - 1;
        const float* dvp = dv + (size_t)ba * (NNBR * 3) + 3 * n;
        const float t0 = -4.0f + (float)j * step;
        const float dx = ti - dvp[0];
        const float dy = t0 - dvp[1];
        const float dz = t0 - dvp[2];
        sEyx[m][j] = __expf(coeff * (dx * dx + dy * dy));
        sEz [m][j] = __expf(coeff * (dz * dz));
    }
    __syncthreads();

    // j = tid>>3: 8-lane broadcast on sEyx (free); k0 = (tid&7)*4:
    // ds_read_b128, 8 lanes cover one 128B row, conflict-free.
    const int j  = tid >> 3;
    const int k0 = (tid & 7) * 4;

    float4 acc = {0.f, 0.f, 0.f, 0.f};
    for (int m = 0; m < M; ++m) {
        const float  e  = sEyx[m][j];
        const float4 ez = *(const float4*)&sEz[m][k0];
        acc.x += e * ez.x;
        acc.y += e * ez.y;
        acc.z += e * ez.z;
        acc.w += e * ez.w;
    }

    out4[tid] = acc;                   // dense, coalesced 4 KB plane per block
}

extern "C" void kernel_launch(void* const* d_in, const int* in_sizes, int n_in,
                              void* d_out, int out_size, void* d_ws, size_t ws_size,
                              hipStream_t stream) {
    const float* dv    = (const float*)d_in[0];   // (4,32,16,3)
    const int*   an    = (const int*)d_in[1];     // (32,16)
    const float* sigma = (const float*)d_in[2];   // (1,)
    float*       out   = (float*)d_out;           // (4,32,32,32,32)

    dim3 grid(4 * 32, G);
    dim3 block(256);
    voxel_kernel<<<grid, block, 0, stream>>>(dv, an, sigma, out);
}